// Round 12
// baseline (260.801 us; speedup 1.0000x reference)
//
#include <hip/hip_runtime.h>

// Hodgkin-Huxley synaptic network, Crank-Nicolson integration.
// R12: 4-lane gate-parallel + COMMON-DENOMINATOR state. Each lane's gate is an
// unnormalized ratio g = p/q:
//   update: p' = beta*p + alpha*q;  q' = Q*q          (NO division)
//   renorm: exact pow2 rescale so q stays in +-[0.5,1) (bit ops, ratio exact)
// Membrane absorbs all 4 denominators into ONE rcp:
//   A=pm^3*ph, B=qm^3*qh, C=pn^4, D=qn^4, W=B*D*qy
//   denW = A*D*qy + 0.875*C*B*qy + 0.0125*py*B*D + 1.0025*W   ( = den * W )
//   numW = -V*denW + (2V-0.3)*W + 110*A*D*qy - 134.75*C*B*qy  ( = num * W )
//   Vn = numW * rcp(denW)
// Serial spine per step: rcp(denW) -> exp(Vn) -> p',q' glue. 2 trans (was 3).
// Singularity fixup = 3 selects onto (beta, alpha, Q<-1), off the long path.
// 256 waves (1/SIMD); 8-deep z prefetch; separate sigmoid pass.

#if defined(__HIP_DEVICE_COMPILE__)
#define EXP2 __builtin_amdgcn_exp2f
#else
#define EXP2 exp2f
#endif

__device__ __forceinline__ float rcpf(float x) { return __builtin_amdgcn_rcpf(x); }

template<int CTRL>
__device__ __forceinline__ float qp(float x) {
#if defined(__HIP_DEVICE_COMPILE__)
    return __int_as_float(__builtin_amdgcn_mov_dpp(__float_as_int(x), CTRL, 0xF, 0xF, false));
#else
    return x;   // host pass: never executed, just needs to type-check
#endif
}
#define QB0(x) qp<0x00>(x)   // quad_perm broadcast lane 0
#define QB1(x) qp<0x55>(x)   // broadcast lane 1
#define QB2(x) qp<0xAA>(x)   // broadcast lane 2
#define QB3(x) qp<0xFF>(x)   // broadcast lane 3
#define QSW(x) qp<0xB1>(x)   // quad_perm[1,0,3,2]: lane^1 swap

struct LaneC {
    float cA, cB;            // e = exp2(fma(cA,Vn,cB))
    float cC, cD;            // t = fma(cC,Vn,cD)
    float cE;                // u = fma(-cE,e,1): 1-e (N,M) or 1 (H,y)
    float cH, cK, cL, cM;    // s = fma(cL,br, fma(cM,z, t*fma(cH,e,cK)))
    float cAe, cAz, cAt;     // alpha = fma(cAe,e, fma(cAz,z, cAt*t))
    float sing, fB, fA;      // Vn==sing -> beta=fB, alpha=fA, Q=1
};

// One CN step for a 4-lane quad; gate state is (p,q), g = p/q. Returns Vn.
__device__ __forceinline__ float hh_step4(float& V, float& p, float& q, float z,
                                          const LaneC& C) {
    // gather all four gates' (p,q) via quad broadcasts (DPP, VALU-speed)
    float pn = QB0(p), pm = QB1(p), ph = QB2(p), py = QB3(p);
    float qn = QB0(q), qm = QB1(q), qh = QB2(q), qy = QB3(q);
    // ---- membrane, common-denominator form (one rcp total) ----
    float pm2 = pm * pm,  qm2 = qm * qm;
    float pmh = pm * ph,  qmh = qm * qh;
    float A = pm2 * pmh,  B = qm2 * qmh;      // pm^3 ph, qm^3 qh
    float pn2 = pn * pn,  qn2 = qn * qn;
    float Cc = pn2 * pn2, Dq = qn2 * qn2;     // pn^4, qn^4 (>=0)
    float DQy = Dq * qy;                      // D*qy
    float BQy = B * qy;                       // B*qy
    float BDq = B * Dq;                       // B*D
    float W   = BDq * qy;                     // B*D*qy
    float AD  = A * DQy;                      // m3h * W
    float CB  = Cc * BQy;                     // n4  * W
    float PyB = py * BDq;                     // y   * W
    float denW = __builtin_fmaf(0.0125f, PyB,
                 __builtin_fmaf(0.875f, CB,
                 __builtin_fmaf(1.0025f, W, AD)));
    float rdW  = rcpf(denW);                  // the long pole: starts ASAP
    float preW = __builtin_fmaf(2.0f, V, -0.3f) * W;
    float numW = __builtin_fmaf(-V, denW,
                 __builtin_fmaf(110.0f, AD,
                 __builtin_fmaf(-134.75f, CB, preW)));
    float Vn   = numW * rdW;
    // ---- this lane's gate, division-free p/q update ----
    float e  = EXP2(__builtin_fmaf(C.cA, Vn, C.cB));
    float t  = __builtin_fmaf(C.cC, Vn, C.cD);
    bool fx  = (Vn == C.sing);                // NaN sing on H,y -> false
    float br = QSW(e);                        // lane2 <- lane3's E4
    float w  = t * __builtin_fmaf(C.cH, e, C.cK);
    float s  = __builtin_fmaf(C.cL, br, __builtin_fmaf(C.cM, z, w));
    float u  = __builtin_fmaf(-C.cE, e, 1.0f);
    float Q  = u + s;
    float be = u - s;
    float al = __builtin_fmaf(C.cAe, e, __builtin_fmaf(C.cAz, z, C.cAt * t));
    Q  = fx ? 1.0f : Q;                       // singularity: g'=fB*g+fA exactly
    be = fx ? C.fB : be;
    al = fx ? C.fA : al;
    float pnew = __builtin_fmaf(be, p, al * q);
    float qnew = Q * q;
    // exact pow2 renorm: q -> +-[0.5,1), p scaled by the same 2^k (ratio exact)
    int qb = __float_as_int(qnew);
    int ef = (qb >> 23) & 0xFF;               // biased exponent of qnew
    q = __int_as_float((qb & 0x807FFFFF) | 0x3F000000);   // +-[0.5,1)
    float sc = __int_as_float((253 - ef) << 23);          // 2^(126-ef)
    p = pnew * sc;
    V = Vn;
    return Vn;
}

__global__ __launch_bounds__(64, 1)
void hh_kernel(const float* __restrict__ z, float* __restrict__ out, int N) {
    const int gid   = blockIdx.x * 64 + threadIdx.x; // 0 .. 16383
    const int lane  = gid & 3;
    const int chain = gid >> 2;                      // 0 .. 4095
    const int b = chain >> 7;
    const int l = chain & 127;
    const size_t base = (size_t)b * N * 128 + l;
    const float* zp = z + base;
    float* op = out + base;

    // per-lane gate constants (exp2-domain; C9=1/(9ln2), C12=1/(12ln2))
    LaneC C;
    const float NaNf = __int_as_float(0x7FC00000);
    switch (lane) {
    case 0:  // N gate: e1 = exp((25-Vn)/9)
        C = { -0.1602994490f,  4.0074862250f,  0.02f, -0.5f, 1.0f,
              0.0025f, 0.025f, 0.0f, 0.0f,
              0.0f, 0.0f, 0.05f,
              25.0f, 0.98708396f, 0.0089418778f };   // 0.9935/1.0065, 0.009/1.0065
        break;
    case 1:  // M gate: e2 = exp((-35-Vn)/9)
        C = { -0.1602994490f, -5.6104807150f,  0.182f, 6.37f, 1.0f,
              0.0170329670329670f, 0.025f, 0.0f, 0.0f,
              0.0f, 0.0f, 0.05f,
              -35.0f, 0.86924620f, 0.076545632f };   // 0.93005/1.06995, 0.0819/1.06995
        break;
    case 2:  // H gate: E3 = exp((-90-Vn)/12); s = 0.00625(E3+br); alpha=0.0125E3
        C = { -0.1202245839f, -10.8202125510f, 0.0f, 1.0f, 0.0f,
              0.00625f, 0.0f, 0.00625f, 0.0f,
              0.0125f, 0.0f, 0.0f,
              NaNf, 0.0f, 0.0f };
        break;
    default: // y gate: E4 = exp((Vn+34)/12) (feeds lane2); s = 0.0025+0.025z
        C = {  0.1202245839f,   4.0876358530f, 0.0f, 1.0f, 0.0f,
              0.0f, 0.0025f, 0.0f, 0.025f,
              0.0f, 0.05f, 0.0f,
              NaNf, 0.0f, 0.0f };
        break;
    }

    float V = -70.0f;
    float p = (lane == 2) ? 1.0f : 0.0f;             // n=0, m=0, h=1, y=0
    float q = 1.0f;                                  // g = p/q

    op[0] = -70.0f;                                  // raw V0; pass 2 sigmoids it

    // 8-deep rotating prefetch: z0..z7 = z[t-1 .. t+6]
    float z0 = (0 <= N-2) ? zp[0]   : 0.0f;
    float z1 = (1 <= N-2) ? zp[128] : 0.0f;
    float z2 = (2 <= N-2) ? zp[256] : 0.0f;
    float z3 = (3 <= N-2) ? zp[384] : 0.0f;
    float z4 = (4 <= N-2) ? zp[512] : 0.0f;
    float z5 = (5 <= N-2) ? zp[640] : 0.0f;
    float z6 = (6 <= N-2) ? zp[768] : 0.0f;
    float z7 = (7 <= N-2) ? zp[896] : 0.0f;
    const float* zpre = zp + 8 * 128;                // next load: z[t+7] at t=1
    float* o = op + 128;
    int t = 1;
    // main: loads touch z indices t+7..t+10 <= N-1  ->  t <= N-11
    for (; t <= N - 11; t += 4) {
        float a0 = zpre[0];
        float a1 = zpre[128];
        float a2 = zpre[256];
        float a3 = zpre[384];
        zpre += 512;
        float v0 = hh_step4(V, p, q, z0, C);
        float v1 = hh_step4(V, p, q, z1, C);
        float v2 = hh_step4(V, p, q, z2, C);
        float v3 = hh_step4(V, p, q, z3, C);
        o[0] = v0; o[128] = v1; o[256] = v2; o[384] = v3;   // all lanes: same value
        o += 512;
        z0 = z4; z1 = z5; z2 = z6; z3 = z7;
        z4 = a0; z5 = a1; z6 = a2; z7 = a3;
    }
    // tail: per-step shift; refill z7 while in range
    for (; t < N; ++t) {
        float v0 = hh_step4(V, p, q, z0, C);
        *o = v0;
        o += 128;
        z0 = z1; z1 = z2; z2 = z3; z3 = z4; z4 = z5; z5 = z6; z6 = z7;
        z7 = (t + 7 <= N - 1) ? zpre[0] : 0.0f;      // z[t+7] for step t+8
        zpre += 128;
    }
}

// Pass 2: in-place sigmoid((v - VT)/KP) over the whole output, float4.
__global__ __launch_bounds__(256)
void sig_kernel(float4* __restrict__ v, int n4c) {
    int i = blockIdx.x * 256 + threadIdx.x;
    if (i < n4c) {
        float4 x = v[i];
        x.x = rcpf(1.0f + EXP2(__builtin_fmaf(-0.48089834664f, x.x, -9.6179669328f)));
        x.y = rcpf(1.0f + EXP2(__builtin_fmaf(-0.48089834664f, x.y, -9.6179669328f)));
        x.z = rcpf(1.0f + EXP2(__builtin_fmaf(-0.48089834664f, x.z, -9.6179669328f)));
        x.w = rcpf(1.0f + EXP2(__builtin_fmaf(-0.48089834664f, x.w, -9.6179669328f)));
        v[i] = x;
    }
}

extern "C" void kernel_launch(void* const* d_in, const int* in_sizes, int n_in,
                              void* d_out, int out_size, void* d_ws, size_t ws_size,
                              hipStream_t stream) {
    const float* z = (const float*)d_in[0];
    float* out = (float*)d_out;
    const int B = 32, L = 128;
    const int N = in_sizes[0] / (B * L);             // 2000
    dim3 grid(B * L * 4 / 64), block(64);            // 4 lanes/chain -> 256 waves
    hipLaunchKernelGGL(hh_kernel, grid, block, 0, stream, z, out, N);
    const int n4c = out_size / 4;                    // out_size divisible by 4
    dim3 sgrid((n4c + 255) / 256), sblock(256);
    hipLaunchKernelGGL(sig_kernel, sgrid, sblock, 0, stream, (float4*)out, n4c);
}